// Round 1
// baseline (223.444 us; speedup 1.0000x reference)
//
#include <hip/hip_runtime.h>
#include <math.h>

// Elementwise B-spline (KAN-style) activation:
//   out = bw * silu(x) + sw * lerp(s[il], s[il+1], frac)
// where s[g] = dot(basis_values[g,:], control_points) (G=3 scalars, computed
// per-thread from wave-uniform loads — linearity of the einsum lets us fold
// the NUM_CP=5 dot product into 3 precomputed scalars).

__global__ __launch_bounds__(256) void bspline_act_v4(
    const float4* __restrict__ x4,
    const float*  __restrict__ cp,    // [5]
    const float*  __restrict__ bw_p,  // [1]
    const float*  __restrict__ sw_p,  // [1]
    const float*  __restrict__ bv,    // [3][5] row-major
    float4*       __restrict__ out4,
    int n4)
{
    int i = blockIdx.x * blockDim.x + threadIdx.x;
    if (i >= n4) return;

    // Wave-uniform scalar precompute (compiler emits s_load / broadcast).
    const float c0 = cp[0], c1 = cp[1], c2 = cp[2], c3 = cp[3], c4 = cp[4];
    const float s0 = bv[0]*c0  + bv[1]*c1  + bv[2]*c2  + bv[3]*c3  + bv[4]*c4;
    const float s1 = bv[5]*c0  + bv[6]*c1  + bv[7]*c2  + bv[8]*c3  + bv[9]*c4;
    const float s2 = bv[10]*c0 + bv[11]*c1 + bv[12]*c2 + bv[13]*c3 + bv[14]*c4;
    const float d0 = s1 - s0, d1 = s2 - s1;
    const float bw = bw_p[0], sw = sw_p[0];

    float4 v = x4[i];
    float xs[4] = {v.x, v.y, v.z, v.w};
    float r[4];
#pragma unroll
    for (int k = 0; k < 4; ++k) {
        float x  = xs[k];
        // grid_idx = (clamp(x,-1,1) - lo)/(hi-lo) * (G-1) = clamp(x,-1,1) + 1
        float t  = fminf(fmaxf(x, -1.0f), 1.0f) + 1.0f;   // in [0,2] exactly
        float fl = floorf(t);
        float fr = t - fl;                                 // frac; 0 when fl==2
        int   il = (int)fl;                                // 0,1,2
        float sl = (il == 0) ? s0 : ((il == 1) ? s1 : s2);
        float dl = (il == 0) ? d0 : d1;                    // il==2 -> fr==0
        float y  = sl + fr * dl;
        float sig = 1.0f / (1.0f + __expf(-x));
        r[k] = bw * (x * sig) + sw * y;
    }
    out4[i] = make_float4(r[0], r[1], r[2], r[3]);
}

// Scalar tail (only launched if n % 4 != 0 — not the case for 8*2048*2048,
// but kept for generality).
__global__ void bspline_act_tail(
    const float* __restrict__ x,
    const float* __restrict__ cp,
    const float* __restrict__ bw_p,
    const float* __restrict__ sw_p,
    const float* __restrict__ bv,
    float*       __restrict__ out,
    int start, int n)
{
    int i = start + blockIdx.x * blockDim.x + threadIdx.x;
    if (i >= n) return;
    const float c0 = cp[0], c1 = cp[1], c2 = cp[2], c3 = cp[3], c4 = cp[4];
    const float s0 = bv[0]*c0  + bv[1]*c1  + bv[2]*c2  + bv[3]*c3  + bv[4]*c4;
    const float s1 = bv[5]*c0  + bv[6]*c1  + bv[7]*c2  + bv[8]*c3  + bv[9]*c4;
    const float s2 = bv[10]*c0 + bv[11]*c1 + bv[12]*c2 + bv[13]*c3 + bv[14]*c4;
    const float d0 = s1 - s0, d1 = s2 - s1;
    const float bw = bw_p[0], sw = sw_p[0];

    float xv = x[i];
    float t  = fminf(fmaxf(xv, -1.0f), 1.0f) + 1.0f;
    float fl = floorf(t);
    float fr = t - fl;
    int   il = (int)fl;
    float sl = (il == 0) ? s0 : ((il == 1) ? s1 : s2);
    float dl = (il == 0) ? d0 : d1;
    float y  = sl + fr * dl;
    float sig = 1.0f / (1.0f + __expf(-xv));
    out[i] = bw * (xv * sig) + sw * y;
}

extern "C" void kernel_launch(void* const* d_in, const int* in_sizes, int n_in,
                              void* d_out, int out_size, void* d_ws, size_t ws_size,
                              hipStream_t stream) {
    const float* x  = (const float*)d_in[0];
    const float* cp = (const float*)d_in[1];
    const float* bw = (const float*)d_in[2];
    const float* sw = (const float*)d_in[3];
    const float* bv = (const float*)d_in[4];
    float* out = (float*)d_out;

    const int n  = in_sizes[0];
    const int n4 = n / 4;
    const int rem_start = n4 * 4;

    if (n4 > 0) {
        const int block = 256;
        const int grid  = (n4 + block - 1) / block;
        bspline_act_v4<<<grid, block, 0, stream>>>(
            (const float4*)x, cp, bw, sw, bv, (float4*)out, n4);
    }
    if (rem_start < n) {
        const int rem = n - rem_start;
        bspline_act_tail<<<(rem + 255) / 256, 256, 0, stream>>>(
            x, cp, bw, sw, bv, out, rem_start, n);
    }
}